// Round 3
// baseline (407.378 us; speedup 1.0000x reference)
//
#include <hip/hip_runtime.h>
#include <hip/hip_bf16.h>
#include <stdint.h>

#define D      256
#define K      8192
#define NROWS  32768          // 16 * 2048
#define QELEMS 8388608        // NROWS * D
// d_out layout (flat f32): [0,QELEMS) quantized, [QELEMS,QELEMS+NROWS) idx, [QELEMS+NROWS] loss

typedef __attribute__((ext_vector_type(8))) short bf16x8;
typedef __attribute__((ext_vector_type(4))) float f32x4;
typedef unsigned int u32;
typedef unsigned short u16;

__device__ __forceinline__ u16 f2bf(float f) {
    u32 b = __float_as_uint(f);
    return (u16)((b + 0x7fffu + ((b >> 16) & 1u)) >> 16);   // RNE
}
__device__ __forceinline__ float bf2f(u16 h) {
    return __uint_as_float((u32)h << 16);
}

// ---------------------------------------------------------------------------
// Prep: cb fp32 -> ch bf16, se[k] = ||cb[k]||^2 (fp32 + bf16), zero loss acc.
__global__ __launch_bounds__(256) void vq_prep_kernel(
    const float* __restrict__ cb, u16* __restrict__ ch,
    float* __restrict__ se, u16* __restrict__ seh, float* __restrict__ loss_sum) {
    int row = blockIdx.x * 4 + (threadIdx.x >> 6);
    int l = threadIdx.x & 63;
    float4 v = *(const float4*)(cb + (size_t)row * D + l * 4);
    ushort4 o;
    o.x = f2bf(v.x); o.y = f2bf(v.y); o.z = f2bf(v.z); o.w = f2bf(v.w);
    *(ushort4*)(ch + (size_t)row * D + l * 4) = o;
    float s = v.x * v.x + v.y * v.y + v.z * v.z + v.w * v.w;
    #pragma unroll
    for (int off = 32; off > 0; off >>= 1) s += __shfl_down(s, off, 64);
    if (l == 0) { se[row] = s; seh[row] = f2bf(s); }
    if (blockIdx.x == 0 && threadIdx.x == 0) *loss_sum = 0.f;
}

// ---------------------------------------------------------------------------
// Filter v4: 128 rows/block, 512 thr (8 waves), grid 256 = 1 block/CU
// (halves per-CU L2 codebook traffic vs 64-row blocks: 4 MiB/CU).
// Wave (m_w = wave&3, n_w = wave>>2): owns 16-code slice m_w of each 64-code
// tile and row-half n_w (64 rows, Bf[4][8] = 128 VGPR). Per c-iter: 1
// ds_read_b128 feeds 4 MFMA. Codebook tile (64x256, 32 KB) triple-buffered in
// LDS via global_load_lds with COUNTED vmcnt(8) (2 tiles in flight, never
// vmcnt(0) in loop; tail peeled at vmcnt(4)/vmcnt(0)). Two raw s_barriers per
// tile: leading (after vmcnt) publishes all waves' stage chunks; trailing
// protects buffer reuse. se read from LDS (bf16) so in-loop VMEM is exactly
// 4 stage loads/wave/tile. Candidates: 16 (m_w,l4) groups x top-2 per row ->
// LDS merge -> 8 slots x best-2-of-union = 16. Rescore unchanged.
__global__ __launch_bounds__(512, 2) void vq_filter_kernel(
    const u16* __restrict__ ch, const float* __restrict__ x,
    const u16* __restrict__ seh, u32* __restrict__ cand)
{
    __shared__ union {
        u16 as[3][16384];                          // 3 x 32 KB tile buffers
        struct { float mv[128 * 33]; u32 mc[128 * 33]; } mg;   // merge overlay
    } S;
    __shared__ u16 seL[8192];                      // bf16 ||e||^2, 16 KB

    const int tid  = threadIdx.x;
    const int lane = tid & 63;
    const int wave = tid >> 6;         // 0..7
    const int m_w  = wave & 3;         // code slice (16 codes of 64-code tile)
    const int n_w  = wave >> 2;        // row half (64 rows of 128-row block)
    const int l15  = lane & 15;
    const int l4   = lane >> 4;        // 0..3
    const int row0 = blockIdx.x * 128;

    // ---- seL: copy bf16 norms to LDS (16384 B, 512 thr x 2 x 16 B) ----
    {
        uint4* dl = (uint4*)seL;
        const uint4* sg = (const uint4*)seh;
        dl[tid] = sg[tid];
        dl[tid + 512] = sg[tid + 512];
    }

    // ---- B operand: 64 rows (row-half n_w) x 256 d in registers ----
    bf16x8 Bf[4][8];                   // 128 VGPRs
    #pragma unroll
    for (int nt = 0; nt < 4; ++nt) {
        const float* xr = x + (size_t)(row0 + n_w * 64 + nt * 16 + l15) * D + l4 * 8;
        #pragma unroll
        for (int c = 0; c < 8; ++c) {
            float4 a = *(const float4*)(xr + c * 32);
            float4 b = *(const float4*)(xr + c * 32 + 4);
            bf16x8 f;
            f[0] = (short)f2bf(a.x); f[1] = (short)f2bf(a.y);
            f[2] = (short)f2bf(a.z); f[3] = (short)f2bf(a.w);
            f[4] = (short)f2bf(b.x); f[5] = (short)f2bf(b.y);
            f[6] = (short)f2bf(b.z); f[7] = (short)f2bf(b.w);
            Bf[nt][c] = f;
        }
    }

    // per-lane top-2 (value, code) per nt row-group
    float b0[4], b1[4]; int c0[4], c1[4];
    #pragma unroll
    for (int nt = 0; nt < 4; ++nt) { b0[nt] = 1e30f; b1[nt] = 1e30f; c0[nt] = 0; c1[nt] = 0; }

    // ---- staging: tile = 32 chunks of 1 KB; wave w stages chunks 4w..4w+3.
    // chunk g = w*4+i holds frag (d-chunk c=w, code-group m=i): codes
    // kt+i*16+l15, d-bytes w*64 + l4*16. LDS dest linear (HW adds lane*16B).
#define STAGE(TILE, BUF) do {                                                 \
    const int _kn = (TILE) << 6;                                              \
    _Pragma("unroll")                                                         \
    for (int i = 0; i < 4; ++i) {                                             \
        const u16* gp = ch + (size_t)(_kn + i * 16 + l15) * D + wave * 32 + l4 * 8; \
        u16* lb = &S.as[(BUF)][(size_t)(wave * 4 + i) * 512];                 \
        __builtin_amdgcn_global_load_lds(                                     \
            (const __attribute__((address_space(1))) u32*)gp,                 \
            (__attribute__((address_space(3))) u32*)lb, 16, 0, 0);            \
    }                                                                         \
} while (0)

#define EPI(NT, A) do {                                                       \
    float t0 = fmaf(-2.f, (A)[0], _se0);                                      \
    float t1 = fmaf(-2.f, (A)[1], _se1);                                      \
    float t2 = fmaf(-2.f, (A)[2], _se2);                                      \
    float t3 = fmaf(-2.f, (A)[3], _se3);                                      \
    float tmn = fminf(fminf(t0, t1), fminf(t2, t3));                          \
    if (tmn < b1[NT]) {                                                       \
        float tv[4] = {t0, t1, t2, t3};                                       \
        _Pragma("unroll")                                                     \
        for (int r = 0; r < 4; ++r) {                                         \
            float t = tv[r];                                                  \
            int cv = _kt + m_w * 16 + l4 * 4 + r;                             \
            bool in0 = t < b0[NT];                                            \
            bool in1 = t < b1[NT];                                            \
            float ob0 = b0[NT]; int oc0 = c0[NT];                             \
            b1[NT] = in0 ? ob0 : (in1 ? t  : b1[NT]);                         \
            c1[NT] = in0 ? oc0 : (in1 ? cv : c1[NT]);                         \
            b0[NT] = in0 ? t  : ob0;                                          \
            c0[NT] = in0 ? cv : oc0;                                          \
        }                                                                     \
    }                                                                         \
} while (0)

    // BODY(T): [stage T+2][vmcnt(N)][barrier][ds_read+MFMA+epi][barrier]
#define BODY(T, DO_STAGE, VMN) do {                                           \
    if (DO_STAGE) STAGE((T) + 2, ((T) + 2) % 3);                              \
    asm volatile("s_waitcnt vmcnt(" #VMN ")" ::: "memory");                   \
    __builtin_amdgcn_s_barrier();                                             \
    const int _kt = (T) << 6;                                                 \
    const u16* _as = &S.as[(T) % 3][0];                                       \
    f32x4 acc0 = {0.f,0.f,0.f,0.f}, acc1 = {0.f,0.f,0.f,0.f};                 \
    f32x4 acc2 = {0.f,0.f,0.f,0.f}, acc3 = {0.f,0.f,0.f,0.f};                 \
    _Pragma("unroll")                                                         \
    for (int c = 0; c < 8; ++c) {                                             \
        bf16x8 Af = *(const bf16x8*)(_as + (size_t)(c * 4 + m_w) * 512 + lane * 8); \
        acc0 = __builtin_amdgcn_mfma_f32_16x16x32_bf16(Af, Bf[0][c], acc0, 0, 0, 0); \
        acc1 = __builtin_amdgcn_mfma_f32_16x16x32_bf16(Af, Bf[1][c], acc1, 0, 0, 0); \
        acc2 = __builtin_amdgcn_mfma_f32_16x16x32_bf16(Af, Bf[2][c], acc2, 0, 0, 0); \
        acc3 = __builtin_amdgcn_mfma_f32_16x16x32_bf16(Af, Bf[3][c], acc3, 0, 0, 0); \
    }                                                                         \
    ushort4 _sh = *(const ushort4*)(seL + _kt + m_w * 16 + l4 * 4);           \
    float _se0 = bf2f(_sh.x), _se1 = bf2f(_sh.y);                             \
    float _se2 = bf2f(_sh.z), _se3 = bf2f(_sh.w);                             \
    EPI(0, acc0); EPI(1, acc1); EPI(2, acc2); EPI(3, acc3);                   \
    __builtin_amdgcn_s_barrier();                                             \
} while (0)

    // prologue: stage tiles 0,1; full drain once (also publishes seL)
    STAGE(0, 0);
    STAGE(1, 1);
    __syncthreads();

    #pragma unroll 1
    for (int t = 0; t < 126; ++t) BODY(t, 1, 8);
    BODY(126, 0, 4);
    BODY(127, 0, 0);

#undef BODY
#undef EPI
#undef STAGE

    // ---- cross-wave merge: 16 (m_w,l4) groups/row -> 8 slots, top-2-of-union
    // overlay on S (all tile reads done at trailing barrier of tile 127).
    #pragma unroll
    for (int nt = 0; nt < 4; ++nt) {
        int rl = n_w * 64 + nt * 16 + l15;             // 0..127
        int g  = m_w * 4 + l4;                         // 0..15
        S.mg.mv[rl * 33 + g * 2]     = b0[nt];
        S.mg.mv[rl * 33 + g * 2 + 1] = b1[nt];
        S.mg.mc[rl * 33 + g * 2]     = (u32)c0[nt];
        S.mg.mc[rl * 33 + g * 2 + 1] = (u32)c1[nt];
    }
    __syncthreads();

    for (int tsk = tid; tsk < 1024; tsk += 512) {
        int row = tsk >> 3, m = tsk & 7;               // merge groups 2m, 2m+1
        const float* v  = S.mg.mv + row * 33 + m * 4;
        const u32*   cc = S.mg.mc + row * 33 + m * 4;
        float v00 = v[0],  v01 = v[1],  v10 = v[2],  v11 = v[3];
        u32   c00 = cc[0], c01 = cc[1], c10 = cc[2], c11 = cc[3];
        bool  aw  = v00 <= v10;
        u32   w0c = aw ? c00 : c10;
        float s1  = aw ? v10 : v00; u32 s1c = aw ? c10 : c00;  // loser of firsts
        float s2  = aw ? v01 : v11; u32 s2c = aw ? c01 : c11;  // winner's second
        u32   w1c = (s2 <= s1) ? s2c : s1c;
        cand[(size_t)(row0 + row) * 16 + m * 2]     = w0c;
        cand[(size_t)(row0 + row) * 16 + m * 2 + 1] = w1c;
    }
}

// ---------------------------------------------------------------------------
// Rescore + output: one wave per row. Coalesced float4 dots over the 16
// candidates (butterfly reduce), fp32 argmin, write quantized + idx +
// block-reduced loss partial (one atomic per block).
__global__ __launch_bounds__(1024) void vq_rescore_kernel(
    const float* __restrict__ x, const float* __restrict__ cb,
    const float* __restrict__ se, const u32* __restrict__ cand,
    float* __restrict__ out, float* __restrict__ loss_sum)
{
    const int wave = threadIdx.x >> 6;
    const int lane = threadIdx.x & 63;
    const int row  = blockIdx.x * 16 + wave;

    float4 xv = *(const float4*)(x + (size_t)row * D + lane * 4);
    float sx = xv.x * xv.x + xv.y * xv.y + xv.z * xv.z + xv.w * xv.w;
    #pragma unroll
    for (int o = 1; o < 64; o <<= 1) sx += __shfl_xor(sx, o, 64);

    u32 myc = cand[(size_t)row * 16 + (lane & 15)];
    float best = 1e30f; int bk = 0x7fffffff;
    #pragma unroll 4
    for (int j = 0; j < 16; ++j) {
        int code = __shfl((int)myc, j, 64);
        float4 ev = *(const float4*)(cb + (size_t)code * D + lane * 4);
        float p = xv.x * ev.x + xv.y * ev.y + xv.z * ev.z + xv.w * ev.w;
        #pragma unroll
        for (int o = 1; o < 64; o <<= 1) p += __shfl_xor(p, o, 64);
        float dist = (sx + se[code]) - 2.0f * p;
        if (dist < best || (dist == best && code < bk)) { best = dist; bk = code; }
    }

    float4 q = *(const float4*)(cb + (size_t)bk * D + lane * 4);
    *(float4*)(out + (size_t)row * D + lane * 4) = q;
    float dx = q.x - xv.x, dy = q.y - xv.y, dz = q.z - xv.z, dw = q.w - xv.w;
    float s = dx * dx + dy * dy + dz * dz + dw * dw;
    #pragma unroll
    for (int o = 1; o < 64; o <<= 1) s += __shfl_xor(s, o, 64);
    if (lane == 0) out[QELEMS + row] = (float)bk;

    __shared__ float red[16];
    if (lane == 0) red[wave] = s;
    __syncthreads();
    if (threadIdx.x == 0) {
        float t = 0.f;
        #pragma unroll
        for (int w2 = 0; w2 < 16; ++w2) t += red[w2];
        atomicAdd(loss_sum, t);
    }
}

// ---------------------------------------------------------------------------
__global__ void vq_fin_kernel(const float* __restrict__ loss_sum, float* __restrict__ out) {
    out[QELEMS + NROWS] = 1.25f * (*loss_sum) * (1.0f / (float)QELEMS);
}

// ---------------------------------------------------------------------------
extern "C" void kernel_launch(void* const* d_in, const int* in_sizes, int n_in,
                              void* d_out, int out_size, void* d_ws, size_t ws_size,
                              hipStream_t stream) {
    const float* x  = (const float*)d_in[0];   // [16,2048,256] fp32
    const float* cb = (const float*)d_in[1];   // [8192,256] fp32
    float* out = (float*)d_out;

    // bf16 codebook scratch in d_out bytes [0, 4 MiB) — dead before the
    // rescore kernel (which overwrites it with quantized rows).
    u16* ch = (u16*)d_out;

    char* ws = (char*)d_ws;
    float* loss_sum = (float*)ws;               // @0, 4 B
    float* sebuf    = (float*)(ws + 4096);      // 32 KB fp32 norms
    u16*   seh      = (u16*)(ws + 40960);       // 16 KB bf16 norms
    u32*   cand     = (u32*)(ws + 65536);       // 32768*16*4 = 2 MiB

    vq_prep_kernel<<<K / 4, 256, 0, stream>>>(cb, ch, sebuf, seh, loss_sum);
    vq_filter_kernel<<<NROWS / 128, 512, 0, stream>>>(ch, x, seh, cand);
    vq_rescore_kernel<<<NROWS / 16, 1024, 0, stream>>>(x, cb, sebuf, cand, out, loss_sum);
    vq_fin_kernel<<<1, 1, 0, stream>>>(loss_sum, out);
}

// Round 5
// 398.954 us; speedup vs baseline: 1.0211x; 1.0211x over previous
//
#include <hip/hip_runtime.h>
#include <hip/hip_bf16.h>
#include <stdint.h>

#define D      256
#define K      8192
#define NROWS  32768          // 16 * 2048
#define QELEMS 8388608        // NROWS * D
// d_out layout (flat f32): [0,QELEMS) quantized, [QELEMS,QELEMS+NROWS) idx, [QELEMS+NROWS] loss

typedef __attribute__((ext_vector_type(8))) short bf16x8;
typedef __attribute__((ext_vector_type(4))) float f32x4;
typedef unsigned int u32;
typedef unsigned short u16;

__device__ __forceinline__ u16 f2bf(float f) {
    u32 b = __float_as_uint(f);
    return (u16)((b + 0x7fffu + ((b >> 16) & 1u)) >> 16);   // RNE
}
__device__ __forceinline__ float bf2f(u16 h) {
    return __uint_as_float((u32)h << 16);
}

// ---------------------------------------------------------------------------
// Prep: cb fp32 -> ch bf16, se[k] = ||cb[k]||^2 (fp32 + bf16), zero loss acc.
__global__ __launch_bounds__(256) void vq_prep_kernel(
    const float* __restrict__ cb, u16* __restrict__ ch,
    float* __restrict__ se, u16* __restrict__ seh, float* __restrict__ loss_sum) {
    int row = blockIdx.x * 4 + (threadIdx.x >> 6);
    int l = threadIdx.x & 63;
    float4 v = *(const float4*)(cb + (size_t)row * D + l * 4);
    ushort4 o;
    o.x = f2bf(v.x); o.y = f2bf(v.y); o.z = f2bf(v.z); o.w = f2bf(v.w);
    *(ushort4*)(ch + (size_t)row * D + l * 4) = o;
    float s = v.x * v.x + v.y * v.y + v.z * v.z + v.w * v.w;
    #pragma unroll
    for (int off = 32; off > 0; off >>= 1) s += __shfl_down(s, off, 64);
    if (l == 0) { se[row] = s; seh[row] = f2bf(s); }
    if (blockIdx.x == 0 && threadIdx.x == 0) *loss_sum = 0.f;
}

// ---------------------------------------------------------------------------
// Filter v6 — occupancy experiment on the VERIFIED round-3 structure.
// 64 rows/block, 512 thr (8 waves), grid 512 -> 2 blocks/CU x 8 waves =
// 16 waves/CU (4/SIMD; all prior rounds ran 2/SIMD). LDS = 2x32KB tile dbuf
// + 16KB bf16 seL = exactly 80 KB -> 2 blocks/CU. launch_bounds(512,4) caps
// VGPR at 128 (est ~110). Wave (m_w = wave&3, n_w = wave>>2): 16-code slice
// m_w of each 64-code tile, 32 rows (half n_w) in registers (Bf[2][8]).
// Per c-iter: 1 ds_read_b128 feeds 2 MFMA. Counted vmcnt(4) (stage T+1 in
// flight across the leading barrier; never vmcnt(0) until the last tile).
// Epilogue: t = se - 2*dot, per-lane top-2 min (round-3 formula, VERIFIED).
// Candidates: 16 (m_w,l4) groups x top-2 -> LDS merge -> 8 slots x
// best-2-of-union = 16. Rescore formula untouched (tie semantics!).
__global__ __launch_bounds__(512, 4) void vq_filter_kernel(
    const u16* __restrict__ ch, const float* __restrict__ x,
    const u16* __restrict__ seh, u32* __restrict__ cand)
{
    __shared__ union {
        u16 as[2][16384];                          // 2 x 32 KB tile buffers
        struct { float mv[64 * 33]; u32 mc[64 * 33]; } mg;   // merge overlay
    } S;
    __shared__ __align__(16) u16 seL[8192];        // bf16 ||e||^2, 16 KB

    const int tid  = threadIdx.x;
    const int lane = tid & 63;
    const int wave = tid >> 6;         // 0..7
    const int m_w  = wave & 3;         // code slice (16 codes of 64-code tile)
    const int n_w  = wave >> 2;        // row half (32 rows of 64-row block)
    const int l15  = lane & 15;
    const int l4   = lane >> 4;        // 0..3
    const int row0 = blockIdx.x * 64;

    // ---- seL: copy bf16 norms to LDS (16384 B = 1024 uint4, 512 thr x 2) ----
    {
        uint4* dl = (uint4*)seL;
        const uint4* sg = (const uint4*)seh;
        dl[tid] = sg[tid];
        dl[tid + 512] = sg[tid + 512];
    }

    // ---- B operand: 32 rows (row-half n_w) x 256 d in registers ----
    bf16x8 Bf[2][8];                   // 64 VGPRs
    #pragma unroll
    for (int nt = 0; nt < 2; ++nt) {
        const float* xr = x + (size_t)(row0 + n_w * 32 + nt * 16 + l15) * D + l4 * 8;
        #pragma unroll
        for (int c = 0; c < 8; ++c) {
            float4 a = *(const float4*)(xr + c * 32);
            float4 b = *(const float4*)(xr + c * 32 + 4);
            bf16x8 f;
            f[0] = (short)f2bf(a.x); f[1] = (short)f2bf(a.y);
            f[2] = (short)f2bf(a.z); f[3] = (short)f2bf(a.w);
            f[4] = (short)f2bf(b.x); f[5] = (short)f2bf(b.y);
            f[6] = (short)f2bf(b.z); f[7] = (short)f2bf(b.w);
            Bf[nt][c] = f;
        }
    }

    // per-lane top-2 SMALLEST t (t = se - 2*dot; round-3 verified polarity)
    float b0[2], b1[2]; int c0[2], c1[2];
    #pragma unroll
    for (int nt = 0; nt < 2; ++nt) { b0[nt] = 1e30f; b1[nt] = 1e30f; c0[nt] = 0; c1[nt] = 0; }

    // ---- staging: tile = 32 chunks of 1 KB; wave w stages chunks 4w..4w+3.
    // chunk g = w*4+i = frag (d-chunk c=w, code-group m=i). LDS dest linear
    // (HW adds lane*16B): lane l <-> (code l&15, d-sub (l>>4)*8).
#define STAGE(TILE, BUF) do {                                                 \
    const int _kn = (TILE) << 6;                                              \
    _Pragma("unroll")                                                         \
    for (int i = 0; i < 4; ++i) {                                             \
        const u16* gp = ch + (size_t)(_kn + i * 16 + l15) * D + wave * 32 + l4 * 8; \
        u16* lb = &S.as[(BUF)][(size_t)(wave * 4 + i) * 512];                 \
        __builtin_amdgcn_global_load_lds(                                     \
            (const __attribute__((address_space(1))) u32*)gp,                 \
            (__attribute__((address_space(3))) u32*)lb, 16, 0, 0);            \
    }                                                                         \
} while (0)

#define EPI(NT, A) do {                                                       \
    float t0 = fmaf(-2.f, (A)[0], _se0);                                      \
    float t1 = fmaf(-2.f, (A)[1], _se1);                                      \
    float t2 = fmaf(-2.f, (A)[2], _se2);                                      \
    float t3 = fmaf(-2.f, (A)[3], _se3);                                      \
    float tmn = fminf(fminf(t0, t1), fminf(t2, t3));                          \
    if (tmn < b1[NT]) {                                                       \
        float tv[4] = {t0, t1, t2, t3};                                       \
        _Pragma("unroll")                                                     \
        for (int r = 0; r < 4; ++r) {                                         \
            float t = tv[r];                                                  \
            int cv = _kt + m_w * 16 + l4 * 4 + r;                             \
            bool in0 = t < b0[NT];                                            \
            bool in1 = t < b1[NT];                                            \
            float ob0 = b0[NT]; int oc0 = c0[NT];                             \
            b1[NT] = in0 ? ob0 : (in1 ? t  : b1[NT]);                         \
            c1[NT] = in0 ? oc0 : (in1 ? cv : c1[NT]);                         \
            b0[NT] = in0 ? t  : ob0;                                          \
            c0[NT] = in0 ? cv : oc0;                                          \
        }                                                                     \
    }                                                                         \
} while (0)

    // BODY(T): [stage T+1][vmcnt(N)][barrier][ds_read+MFMA+epi][barrier]
    // steady vmcnt(4): completes STAGE(T), leaves STAGE(T+1)'s 4 in flight.
#define BODY(T, DO_STAGE, VMN) do {                                           \
    if (DO_STAGE) STAGE((T) + 1, ((T) + 1) & 1);                              \
    asm volatile("s_waitcnt vmcnt(" #VMN ")" ::: "memory");                   \
    __builtin_amdgcn_s_barrier();                                             \
    const int _kt = (T) << 6;                                                 \
    const u16* _as = &S.as[(T) & 1][0];                                       \
    f32x4 acc0 = {0.f,0.f,0.f,0.f}, acc1 = {0.f,0.f,0.f,0.f};                 \
    _Pragma("unroll")                                                         \
    for (int c = 0; c < 8; ++c) {                                             \
        bf16x8 Af = *(const bf16x8*)(_as + (size_t)(c * 4 + m_w) * 512 + lane * 8); \
        acc0 = __builtin_amdgcn_mfma_f32_16x16x32_bf16(Af, Bf[0][c], acc0, 0, 0, 0); \
        acc1 = __builtin_amdgcn_mfma_f32_16x16x32_bf16(Af, Bf[1][c], acc1, 0, 0, 0); \
    }                                                                         \
    ushort4 _sh = *(const ushort4*)(seL + _kt + m_w * 16 + l4 * 4);           \
    float _se0 = bf2f(_sh.x), _se1 = bf2f(_sh.y);                             \
    float _se2 = bf2f(_sh.z), _se3 = bf2f(_sh.w);                             \
    EPI(0, acc0); EPI(1, acc1);                                               \
    __builtin_amdgcn_s_barrier();                                             \
} while (0)

    // prologue: stage tile 0; full drain once (also publishes seL)
    STAGE(0, 0);
    __syncthreads();

    #pragma unroll 1
    for (int t = 0; t < 127; ++t) BODY(t, 1, 4);
    BODY(127, 0, 0);

#undef BODY
#undef EPI
#undef STAGE

    // ---- cross-wave merge: 16 (m_w,l4) groups/row -> 8 slots, top-2-of-union
    // overlay on S.as bytes: As[0] last read at tile 126; As[1] (bytes
    // 32768..65535) doesn't overlap the 16896-B merge region. All waves past
    // tile-127 trailing barrier before writes (program order), plus the
    // __syncthreads below before reads.
    #pragma unroll
    for (int nt = 0; nt < 2; ++nt) {
        int rl = n_w * 32 + nt * 16 + l15;             // 0..63
        int g  = m_w * 4 + l4;                         // 0..15
        S.mg.mv[rl * 33 + g * 2]     = b0[nt];
        S.mg.mv[rl * 33 + g * 2 + 1] = b1[nt];
        S.mg.mc[rl * 33 + g * 2]     = (u32)c0[nt];
        S.mg.mc[rl * 33 + g * 2 + 1] = (u32)c1[nt];
    }
    __syncthreads();

    {
        int tsk = tid;                                 // 512 tasks, 512 threads
        int row = tsk >> 3, m = tsk & 7;               // merge groups 2m, 2m+1
        const float* v  = S.mg.mv + row * 33 + m * 4;
        const u32*   cc = S.mg.mc + row * 33 + m * 4;
        float v00 = v[0],  v01 = v[1],  v10 = v[2],  v11 = v[3];
        u32   c00 = cc[0], c01 = cc[1], c10 = cc[2], c11 = cc[3];
        // smallest-2 of the (sorted-pair, sorted-pair) union
        bool  aw  = v00 <= v10;
        u32   w0c = aw ? c00 : c10;
        float s1  = aw ? v10 : v00; u32 s1c = aw ? c10 : c00;  // loser of firsts
        float s2  = aw ? v01 : v11; u32 s2c = aw ? c01 : c11;  // winner's second
        u32   w1c = (s2 <= s1) ? s2c : s1c;
        cand[(size_t)(row0 + row) * 16 + m * 2]     = w0c;
        cand[(size_t)(row0 + row) * 16 + m * 2 + 1] = w1c;
    }
}

// ---------------------------------------------------------------------------
// Rescore + output: one wave per row. Coalesced float4 dots over the 16
// candidates (butterfly reduce), fp32 argmin with the ROUND-0 formula
// (sx + se - 2p at magnitude ~256 — its fp32 tie-collapse must match the
// numpy reference's; do NOT "improve" the numerics), ties -> smallest code.
__global__ __launch_bounds__(1024) void vq_rescore_kernel(
    const float* __restrict__ x, const float* __restrict__ cb,
    const float* __restrict__ se, const u32* __restrict__ cand,
    float* __restrict__ out, float* __restrict__ loss_sum)
{
    const int wave = threadIdx.x >> 6;
    const int lane = threadIdx.x & 63;
    const int row  = blockIdx.x * 16 + wave;

    float4 xv = *(const float4*)(x + (size_t)row * D + lane * 4);
    float sx = xv.x * xv.x + xv.y * xv.y + xv.z * xv.z + xv.w * xv.w;
    #pragma unroll
    for (int o = 1; o < 64; o <<= 1) sx += __shfl_xor(sx, o, 64);

    u32 myc = cand[(size_t)row * 16 + (lane & 15)];
    float best = 1e30f; int bk = 0x7fffffff;
    #pragma unroll 4
    for (int j = 0; j < 16; ++j) {
        int code = __shfl((int)myc, j, 64);
        float4 ev = *(const float4*)(cb + (size_t)code * D + lane * 4);
        float p = xv.x * ev.x + xv.y * ev.y + xv.z * ev.z + xv.w * ev.w;
        #pragma unroll
        for (int o = 1; o < 64; o <<= 1) p += __shfl_xor(p, o, 64);
        float dist = (sx + se[code]) - 2.0f * p;
        if (dist < best || (dist == best && code < bk)) { best = dist; bk = code; }
    }

    float4 q = *(const float4*)(cb + (size_t)bk * D + lane * 4);
    *(float4*)(out + (size_t)row * D + lane * 4) = q;
    float dx = q.x - xv.x, dy = q.y - xv.y, dz = q.z - xv.z, dw = q.w - xv.w;
    float s = dx * dx + dy * dy + dz * dz + dw * dw;
    #pragma unroll
    for (int o = 1; o < 64; o <<= 1) s += __shfl_xor(s, o, 64);
    if (lane == 0) out[QELEMS + row] = (float)bk;

    __shared__ float red[16];
    if (lane == 0) red[wave] = s;
    __syncthreads();
    if (threadIdx.x == 0) {
        float t = 0.f;
        #pragma unroll
        for (int w2 = 0; w2 < 16; ++w2) t += red[w2];
        atomicAdd(loss_sum, t);
    }
}

// ---------------------------------------------------------------------------
__global__ void vq_fin_kernel(const float* __restrict__ loss_sum, float* __restrict__ out) {
    out[QELEMS + NROWS] = 1.25f * (*loss_sum) * (1.0f / (float)QELEMS);
}

// ---------------------------------------------------------------------------
extern "C" void kernel_launch(void* const* d_in, const int* in_sizes, int n_in,
                              void* d_out, int out_size, void* d_ws, size_t ws_size,
                              hipStream_t stream) {
    const float* x  = (const float*)d_in[0];   // [16,2048,256] fp32
    const float* cb = (const float*)d_in[1];   // [8192,256] fp32
    float* out = (float*)d_out;

    // bf16 codebook scratch in d_out bytes [0, 4 MiB) — dead before the
    // rescore kernel (which overwrites it with quantized rows).
    u16* ch = (u16*)d_out;

    char* ws = (char*)d_ws;
    float* loss_sum = (float*)ws;               // @0, 4 B
    float* sebuf    = (float*)(ws + 4096);      // 32 KB fp32 norms
    u16*   seh      = (u16*)(ws + 40960);       // 16 KB bf16 norms
    u32*   cand     = (u32*)(ws + 65536);       // 32768*16*4 = 2 MiB

    vq_prep_kernel<<<K / 4, 256, 0, stream>>>(cb, ch, sebuf, seh, loss_sum);
    vq_filter_kernel<<<NROWS / 64, 512, 0, stream>>>(ch, x, seh, cand);
    vq_rescore_kernel<<<NROWS / 16, 1024, 0, stream>>>(x, cb, sebuf, cand, out, loss_sum);
    vq_fin_kernel<<<1, 1, 0, stream>>>(loss_sum, out);
}